// Round 18
// baseline (198.073 us; speedup 1.0000x reference)
//
#include <hip/hip_runtime.h>

typedef unsigned short ushort_t;
typedef __attribute__((ext_vector_type(8))) short bf16x8;
typedef __attribute__((ext_vector_type(4))) float f32x4;

#define B_SZ   16
#define NQ     4096
#define NKV    77
#define QDIM   320
#define CDIM   768
#define HEADS  8
#define DHEAD  64
#define INNER  512
#define M_ROWS (B_SZ * NQ)   // 65536
#define VT_STR 104

__device__ __forceinline__ ushort_t f2bf(float f) {
  unsigned u = __builtin_bit_cast(unsigned, f);
  u = (u + 0x7fffu + ((u >> 16) & 1u)) >> 16;
  return (ushort_t)u;
}

__device__ __forceinline__ void async16(const ushort_t* g, ushort_t* l) {
  __builtin_amdgcn_global_load_lds(
      (const __attribute__((address_space(1))) unsigned int*)g,
      (__attribute__((address_space(3))) unsigned int*)l,
      16, 0, 0);
}

__device__ __forceinline__ bf16x8 cvt8(f32x4 lo, f32x4 hi) {
  unsigned w0, w1, w2, w3;
  asm("v_cvt_pk_bf16_f32 %0, %1, %2" : "=v"(w0) : "v"(lo[0]), "v"(lo[1]));
  asm("v_cvt_pk_bf16_f32 %0, %1, %2" : "=v"(w1) : "v"(lo[2]), "v"(lo[3]));
  asm("v_cvt_pk_bf16_f32 %0, %1, %2" : "=v"(w2) : "v"(hi[0]), "v"(hi[1]));
  asm("v_cvt_pk_bf16_f32 %0, %1, %2" : "=v"(w3) : "v"(hi[2]), "v"(hi[3]));
  union { unsigned u[4]; bf16x8 v; } cv;
  cv.u[0] = w0; cv.u[1] = w1; cv.u[2] = w2; cv.u[3] = w3;
  return cv.v;
}

// counted waitcnt: loads stay in flight across barriers (T3/T4)
#define VMCNT(N) asm volatile("s_waitcnt vmcnt(" #N ")" ::: "memory")

// ---------------- mask dtype detect + bias table ----------------
__global__ void mask_bias_kernel(const unsigned char* __restrict__ mraw,
                                 float* __restrict__ biasT) {
  __shared__ int s_u8, s_w4;
  if (threadIdx.x == 0) { s_u8 = 0; s_w4 = 0; }
  __syncthreads();
  const int nbytes = B_SZ * NKV;
  for (int i = threadIdx.x; i < nbytes; i += blockDim.x) {
    unsigned char v = mraw[i];
    if (v && (i & 3)) atomicOr(&s_u8, 1);
    if (v && ((i & 7) == 4)) atomicOr(&s_w4, 1);
  }
  __syncthreads();
  int mode = s_u8 ? 0 : (s_w4 ? 1 : 2);
  for (int i = threadIdx.x; i < B_SZ * 80; i += blockDim.x) {
    int b = i / 80, kv = i - b * 80;
    float bias = -2e30f;
    if (kv < NKV) {
      int idx = b * NKV + kv;
      long long m;
      if (mode == 0)      m = (long long)mraw[idx];
      else if (mode == 1) m = (long long)((const int*)mraw)[idx];
      else                m = ((const long long*)mraw)[idx];
      bias = m ? 0.0f : -1e30f;
    }
    biasT[i] = bias;
  }
}

// ---------------- fused prep: ctx cast + all weight transpose-casts --------
#define PREP_T0 236544
#define PREP_T1 400384
#define PREP_T2 1186816
#define PREP_T3 1383424
__global__ void prep_kernel(const float* __restrict__ ctx, ushort_t* __restrict__ cb,
                            const float* __restrict__ Wq, ushort_t* __restrict__ Wqb,
                            const float* __restrict__ Wk, const float* __restrict__ Wv,
                            ushort_t* __restrict__ Wkvb,
                            const float* __restrict__ Wo, ushort_t* __restrict__ Wob) {
  int i = blockIdx.x * blockDim.x + threadIdx.x;
  const int stride = gridDim.x * blockDim.x;
  for (; i < PREP_T3; i += stride) {
    if (i < PREP_T0) {
      float4 v = ((const float4*)ctx)[i];
      ushort4 o;
      o.x = f2bf(v.x); o.y = f2bf(v.y); o.z = f2bf(v.z); o.w = f2bf(v.w);
      ((ushort4*)cb)[i] = o;
    } else if (i < PREP_T1) {
      int j = i - PREP_T0;
      int n = j / QDIM, k = j - n * QDIM;
      Wqb[j] = f2bf(Wq[(size_t)k * INNER + n] * 0.125f);
    } else if (i < PREP_T2) {
      int j = i - PREP_T1;
      int n = j / CDIM, k = j - n * CDIM;
      float v = (n < INNER) ? Wk[(size_t)k * INNER + n]
                            : Wv[(size_t)k * INNER + (n - INNER)];
      Wkvb[j] = f2bf(v);
    } else {
      int j = i - PREP_T2;
      int n = j / INNER, k = j - n * INNER;
      Wob[j] = (n < QDIM) ? f2bf(Wo[(size_t)k * QDIM + n]) : (ushort_t)0;
    }
  }
}

// ---------------- generic 128x128 GEMM (kv projection only) ----------
__global__ __launch_bounds__(256) void gemm_bf16(
    const ushort_t* __restrict__ A, const ushort_t* __restrict__ Bt,
    ushort_t* __restrict__ Cb,
    int K, int Astride, int Bstride, int Cstride) {
  __shared__ ushort_t As[128 * 64];
  __shared__ ushort_t Bs[128 * 64];
  const int tid = threadIdx.x;
  const int wid = tid >> 6, lane = tid & 63;
  const int wr = wid >> 1, wc = wid & 1;
  const int tileM = blockIdx.x * 128, tileN = blockIdx.y * 128;

  f32x4 acc[4][4];
#pragma unroll
  for (int m = 0; m < 4; ++m)
#pragma unroll
    for (int n = 0; n < 4; ++n) acc[m][n] = (f32x4){0.f, 0.f, 0.f, 0.f};

  const int srow = lane >> 3;
  const int scol = (lane & 7) * 8;

  for (int kt = 0; kt < K; kt += 64) {
    __syncthreads();
#pragma unroll
    for (int j = 0; j < 4; ++j) {
      int s = wid * 4 + j;
      const ushort_t* ga = A + (size_t)(tileM + s * 8 + srow) * Astride + kt + scol;
      const ushort_t* gb = Bt + (size_t)(tileN + s * 8 + srow) * Bstride + kt + scol;
      async16(ga, As + s * 512);
      async16(gb, Bs + s * 512);
    }
    __syncthreads();
#pragma unroll
    for (int kc = 0; kc < 2; ++kc) {
      bf16x8 af[4], bfr[4];
#pragma unroll
      for (int m = 0; m < 4; ++m)
        af[m] = *(const bf16x8*)&As[(wr * 64 + m * 16 + (lane & 15)) * 64 + kc * 32 + (lane >> 4) * 8];
#pragma unroll
      for (int n = 0; n < 4; ++n)
        bfr[n] = *(const bf16x8*)&Bs[(wc * 64 + n * 16 + (lane & 15)) * 64 + kc * 32 + (lane >> 4) * 8];
#pragma unroll
      for (int m = 0; m < 4; ++m)
#pragma unroll
        for (int n = 0; n < 4; ++n)
          acc[m][n] = __builtin_amdgcn_mfma_f32_16x16x32_bf16(af[m], bfr[n], acc[m][n], 0, 0, 0);
    }
  }

  const int r0 = tileM + wr * 64;
  const int c0 = tileN + wc * 64;
  const int rl2 = (lane >> 4) * 4;
  const int cl = lane & 15;
#pragma unroll
  for (int m = 0; m < 4; ++m)
#pragma unroll
    for (int n = 0; n < 4; ++n) {
      int col = c0 + n * 16 + cl;
#pragma unroll
      for (int r = 0; r < 4; ++r)
        Cb[(size_t)(r0 + m * 16 + rl2 + r) * Cstride + col] = f2bf(acc[m][n][r]);
    }
}

__global__ void vtrans_kernel(const ushort_t* __restrict__ kvb,
                              ushort_t* __restrict__ vt) {
  const int h = blockIdx.y, b = blockIdx.z;
  const int wid = threadIdx.x >> 6, lane = threadIdx.x & 63;
  const int d = blockIdx.x * 4 + wid;
  ushort_t* dst = vt + (size_t)(b * HEADS + h) * (64 * VT_STR) + d * VT_STR;
  for (int kv = lane; kv < VT_STR; kv += 64)
    dst[kv] = (kv < NKV)
        ? kvb[(size_t)(b * NKV + kv) * 1024 + 512 + h * 64 + d]
        : (ushort_t)0;
}

// ---------------- q-proj, f32-A + 2 blocks/CU synthesis --------------------
// grid (4 Ntiles, 512 Mgroups): same-M blocks adjacent -> x re-reads L2-served.
// Block = 128 rows x 128 cols, 8 waves (2M x 4N), wave 64x32. BK=32, 10 steps.
// Step = A f32 16KB + B 8KB = 24 KB; 3 bufs = 72 KB -> 2 blocks/CU.
// A staged f32 w/ XOR swizzle (qproj_p pattern), cvt8 at frag-build.
__global__ __launch_bounds__(512, 2) void gemm_qproj_f(
    const float* __restrict__ x, const ushort_t* __restrict__ Wt,
    ushort_t* __restrict__ qb) {
  extern __shared__ char sm[];
  const int tid = threadIdx.x, wid = tid >> 6, lane = tid & 63;
  const int rl = lane & 15, g = lane >> 4;
  const int wr = wid & 1, wc = wid >> 1;
  const int Nbase = blockIdx.x * 128;
  const size_t Mbase = (size_t)blockIdx.y * 128;

  // A: 128 rows x 128 B/step = 1024 chunks of 16B, 2/thread
  size_t asrc[2]; unsigned adst[2];
#pragma unroll
  for (int i = 0; i < 2; ++i) {
    int c = tid + i * 512, row = c >> 3, c16 = c & 7;
    asrc[i] = (Mbase + row) * 1280 + (unsigned)((c16 * 16) ^ ((row & 7) << 4));
    adst[i] = c * 16;
  }
  // B: 128 rows x 64 B/step = 512 chunks, 1/thread
  size_t bsrc; unsigned bdst;
  {
    int row = tid >> 2, c16 = tid & 3;
    bsrc = (size_t)(Nbase + row) * 640 + (unsigned)((c16 * 16) ^ ((row & 3) << 4));
    bdst = 16384 + tid * 16;
  }
  const char* xB = (const char*)x;
  const char* WtB = (const char*)Wt;

  f32x4 acc[4][2];
#pragma unroll
  for (int m = 0; m < 4; ++m)
#pragma unroll
    for (int n = 0; n < 2; ++n) acc[m][n] = (f32x4){0.f, 0.f, 0.f, 0.f};

#define FSTG(K)                                                             \
  {                                                                         \
    char* bb = sm + (unsigned)((K) % 3) * 24576u;                           \
    _Pragma("unroll")                                                       \
    for (int i = 0; i < 2; ++i)                                             \
      async16((const ushort_t*)(xB + asrc[i] + (size_t)(K) * 128),          \
              (ushort_t*)(bb + adst[i]));                                   \
    async16((const ushort_t*)(WtB + bsrc + (size_t)(K) * 64),               \
            (ushort_t*)(bb + bdst));                                        \
  }

  FSTG(0)
  FSTG(1)
  for (int s = 0; s < 10; ++s) {
    if (s < 8)       { FSTG(s + 2) VMCNT(6); }
    else if (s == 8) { VMCNT(3); }
    else             { VMCNT(0); }
    __builtin_amdgcn_sched_barrier(0);
    __builtin_amdgcn_s_barrier();
    __builtin_amdgcn_sched_barrier(0);

    const char* Ab = sm + (unsigned)(s % 3) * 24576u;
    const char* Bb = Ab + 16384;
    bf16x8 af[4], bfr[2];
#pragma unroll
    for (int m = 0; m < 4; ++m) {
      const int row = wr * 64 + m * 16 + rl;
      const int sw = (row & 7) << 4;
      f32x4 lo = *(const f32x4*)(Ab + row * 128 + ((g * 32) ^ sw));
      f32x4 hi = *(const f32x4*)(Ab + row * 128 + ((g * 32 + 16) ^ sw));
      af[m] = cvt8(lo, hi);
    }
#pragma unroll
    for (int n = 0; n < 2; ++n) {
      const int row = wc * 32 + n * 16 + rl;
      bfr[n] = *(const bf16x8*)(Bb + row * 64 + ((g * 16) ^ ((row & 3) << 4)));
    }
#pragma unroll
    for (int m = 0; m < 4; ++m)
#pragma unroll
      for (int n = 0; n < 2; ++n)
        acc[m][n] = __builtin_amdgcn_mfma_f32_16x16x32_bf16(af[m], bfr[n], acc[m][n], 0, 0, 0);
    __builtin_amdgcn_sched_barrier(0);
    __builtin_amdgcn_s_barrier();
    __builtin_amdgcn_sched_barrier(0);
  }

  // epilogue: acc -> LDS (stride 136 shorts) -> coalesced 16B stores
  __syncthreads();
  ushort_t* eb = (ushort_t*)sm;
#pragma unroll
  for (int m = 0; m < 4; ++m)
#pragma unroll
    for (int n = 0; n < 2; ++n)
#pragma unroll
      for (int r = 0; r < 4; ++r)
        eb[(wr * 64 + m * 16 + g * 4 + r) * 136 + wc * 32 + n * 16 + rl] = f2bf(acc[m][n][r]);
  __syncthreads();
#pragma unroll
  for (int i = 0; i < 4; ++i) {
    int c = tid + i * 512, row = c >> 4, c8 = c & 15;
    *(bf16x8*)(qb + (Mbase + row) * 512 + Nbase + c8 * 8) =
        *(const bf16x8*)(eb + row * 136 + c8 * 8);
  }
}

// ---------------- out-proj, pipelined (r5/r11 version) ---------------------
__global__ __launch_bounds__(512, 2) void gemm_oproj_p(
    const ushort_t* __restrict__ A, const ushort_t* __restrict__ Wt,
    const float* __restrict__ bo, float* __restrict__ out) {
  extern __shared__ char sm[];
  const int tid = threadIdx.x, wid = tid >> 6, lane = tid & 63;
  const int rl = lane & 15, g = lane >> 4;
  const int wr = wid & 1, wc = wid >> 1;
  const size_t Mbase = (size_t)blockIdx.x * 128;

  size_t asrc; unsigned adst;
  {
    int c = tid, row = c >> 2, c16 = c & 3;
    asrc = (Mbase + row) * 1024 + (unsigned)((c16 * 16) ^ ((row & 3) << 4));
    adst = c * 16;
  }
  size_t bsrc[3]; unsigned bdst[3];
#pragma unroll
  for (int i = 0; i < 3; ++i) {
    int c = tid + i * 512, row = c >> 2, c16 = c & 3;
    bsrc[i] = (size_t)row * 1024 + (unsigned)((c16 * 16) ^ ((row & 3) << 4));
    bdst[i] = 8192 + c * 16;
  }
  const char* AB = (const char*)A;
  const char* WtB = (const char*)Wt;

  f32x4 acc[4][6];
#pragma unroll
  for (int m = 0; m < 4; ++m)
#pragma unroll
    for (int n = 0; n < 6; ++n) acc[m][n] = (f32x4){0.f, 0.f, 0.f, 0.f};

#define OSTAGE(K)                                                           \
  {                                                                         \
    char* bb = sm + (unsigned)((K) % 3) * 32768u;                           \
    async16((const ushort_t*)(AB + asrc + (size_t)(K) * 64),                \
            (ushort_t*)(bb + adst));                                        \
    _Pragma("unroll")                                                       \
    for (int i = 0; i < 3; ++i)                                             \
      async16((const ushort_t*)(WtB + bsrc[i] + (size_t)(K) * 64),          \
              (ushort_t*)(bb + bdst[i]));                                   \
  }

  OSTAGE(0)
  OSTAGE(1)
  for (int s = 0; s < 16; ++s) {
    if (s < 14) OSTAGE(s + 2)
    if (s < 14)       { VMCNT(8); }
    else if (s == 14) { VMCNT(4); }
    else              { VMCNT(0); }
    __builtin_amdgcn_sched_barrier(0);
    __builtin_amdgcn_s_barrier();
    __builtin_amdgcn_sched_barrier(0);

    const char* Ab = sm + (unsigned)(s % 3) * 32768u;
    const char* Bb = Ab + 8192;
    bf16x8 af[4], bfr[6];
#pragma unroll
    for (int m = 0; m < 4; ++m) {
      const int row = wr * 64 + m * 16 + rl;
      af[m] = *(const bf16x8*)(Ab + row * 64 + ((g * 16) ^ ((row & 3) << 4)));
    }
#pragma unroll
    for (int n = 0; n < 6; ++n) {
      const int row = wc * 96 + n * 16 + rl;
      bfr[n] = *(const bf16x8*)(Bb + row * 64 + ((g * 16) ^ ((row & 3) << 4)));
    }
#pragma unroll
    for (int m = 0; m < 4; ++m)
#pragma unroll
      for (int n = 0; n < 6; ++n)
        acc[m][n] = __builtin_amdgcn_mfma_f32_16x16x32_bf16(af[m], bfr[n], acc[m][n], 0, 0, 0);
    __builtin_amdgcn_sched_barrier(0);
    __builtin_amdgcn_s_barrier();
    __builtin_amdgcn_sched_barrier(0);
  }

  const size_t r0 = Mbase + wr * 64;
  const int c0 = wc * 96;
#pragma unroll
  for (int n = 0; n < 6; ++n) {
    int col = c0 + n * 16 + rl;
    if (col < QDIM) {
      float bv = bo[col];
#pragma unroll
      for (int m = 0; m < 4; ++m)
#pragma unroll
        for (int r = 0; r < 4; ++r)
          out[(r0 + m * 16 + g * 4 + r) * QDIM + col] = acc[m][n][r] + bv;
    }
  }
}

// ---------------- fused attention (r2 version, unchanged) ----------------
__global__ __launch_bounds__(256) void attn_kernel(
    const ushort_t* __restrict__ qb, const ushort_t* __restrict__ kvb,
    const ushort_t* __restrict__ vt, const float* __restrict__ biasT,
    ushort_t* __restrict__ ab) {
  __shared__ ushort_t Vt[64 * VT_STR];
  __shared__ ushort_t P[4 * 16 * VT_STR];
  const int qt = blockIdx.x, h = blockIdx.y, b = blockIdx.z;
  const int tid = threadIdx.x, wid = tid >> 6, lane = tid & 63;
  const int rl = lane & 15;
  const int kh = (lane >> 4) * 8;

  const ushort_t* vtg = vt + (size_t)(b * HEADS + h) * (64 * VT_STR);
  for (int i = tid; i < 832; i += 256) async16(vtg + i * 8, Vt + i * 8);
  for (int i = tid; i < 832; i += 256)
    *(bf16x8*)&P[i * 8] = (bf16x8){0, 0, 0, 0, 0, 0, 0, 0};

  bf16x8 kf[5][2];
  float bias_v[5];
#pragma unroll
  for (int nt = 0; nt < 5; ++nt) {
    int kv = nt * 16 + rl;
    bias_v[nt] = biasT[b * 80 + kv];
    kf[nt][0] = (bf16x8){0, 0, 0, 0, 0, 0, 0, 0};
    kf[nt][1] = (bf16x8){0, 0, 0, 0, 0, 0, 0, 0};
    if (kv < NKV) {
      const ushort_t* kp = &kvb[(size_t)(b * NKV + kv) * 1024 + h * 64 + kh];
      kf[nt][0] = *(const bf16x8*)kp;
      kf[nt][1] = *(const bf16x8*)(kp + 32);
    }
  }
  __syncthreads();

  const int qbase = b * NQ + qt * 256;
  const int pbase = wid * (16 * VT_STR);
#pragma unroll 1
  for (int chunk = 0; chunk < 4; ++chunk) {
    if (chunk) __syncthreads();
    const int row0 = chunk * 64 + wid * 16;

    const ushort_t* qp = &qb[(size_t)(qbase + row0 + rl) * INNER + h * 64 + kh];
    bf16x8 qf0 = *(const bf16x8*)qp;
    bf16x8 qf1 = *(const bf16x8*)(qp + 32);

    f32x4 s[5];
#pragma unroll
    for (int nt = 0; nt < 5; ++nt) {
      s[nt] = (f32x4){0.f, 0.f, 0.f, 0.f};
      s[nt] = __builtin_amdgcn_mfma_f32_16x16x32_bf16(qf0, kf[nt][0], s[nt], 0, 0, 0);
      s[nt] = __builtin_amdgcn_mfma_f32_16x16x32_bf16(qf1, kf[nt][1], s[nt], 0, 0, 0);
    }

    float mx[4] = {-3.0e38f, -3.0e38f, -3.0e38f, -3.0e38f};
#pragma unroll
    for (int nt = 0; nt < 5; ++nt)
#pragma unroll
      for (int r = 0; r < 4; ++r) {
        float v = s[nt][r] + bias_v[nt];
        s[nt][r] = v;
        mx[r] = fmaxf(mx[r], v);
      }
#pragma unroll
    for (int d = 1; d < 16; d <<= 1)
#pragma unroll
      for (int r = 0; r < 4; ++r) mx[r] = fmaxf(mx[r], __shfl_xor(mx[r], d, 64));

    float sm_[4] = {0.f, 0.f, 0.f, 0.f};
#pragma unroll
    for (int nt = 0; nt < 5; ++nt)
#pragma unroll
      for (int r = 0; r < 4; ++r) {
        float p = __expf(s[nt][r] - mx[r]);
        s[nt][r] = p;
        sm_[r] += p;
      }
#pragma unroll
    for (int d = 1; d < 16; d <<= 1)
#pragma unroll
      for (int r = 0; r < 4; ++r) sm_[r] += __shfl_xor(sm_[r], d, 64);

    float rcp[4];
#pragma unroll
    for (int r = 0; r < 4; ++r) rcp[r] = 1.0f / sm_[r];

#pragma unroll
    for (int nt = 0; nt < 5; ++nt)
#pragma unroll
      for (int r = 0; r < 4; ++r)
        P[pbase + ((lane >> 4) * 4 + r) * VT_STR + nt * 16 + rl] = f2bf(s[nt][r]);

    f32x4 o[4];
#pragma unroll
    for (int n = 0; n < 4; ++n) o[n] = (f32x4){0.f, 0.f, 0.f, 0.f};
#pragma unroll
    for (int kc = 0; kc < 3; ++kc) {
      bf16x8 pf = *(const bf16x8*)&P[pbase + rl * VT_STR + kc * 32 + kh];
#pragma unroll
      for (int n = 0; n < 4; ++n) {
        bf16x8 vf = *(const bf16x8*)&Vt[(n * 16 + rl) * VT_STR + kc * 32 + kh];
        o[n] = __builtin_amdgcn_mfma_f32_16x16x32_bf16(pf, vf, o[n], 0, 0, 0);
      }
    }

#pragma unroll
    for (int n = 0; n < 4; ++n)
#pragma unroll
      for (int r = 0; r < 4; ++r)
        P[pbase + ((lane >> 4) * 4 + r) * VT_STR + n * 16 + rl] = f2bf(o[n][r] * rcp[r]);

    __syncthreads();

    {
      const int rflat = tid >> 2, d0 = (tid & 3) * 16;
      const ushort_t* src = &P[(rflat >> 4) * (16 * VT_STR) + (rflat & 15) * VT_STR + d0];
      ushort_t* dst = &ab[(size_t)(qbase + chunk * 64 + rflat) * INNER + h * 64 + d0];
      *(bf16x8*)dst = *(const bf16x8*)src;
      *(bf16x8*)(dst + 8) = *(const bf16x8*)(src + 8);
    }
  }
}

// ---------------- host ----------------
extern "C" void kernel_launch(void* const* d_in, const int* in_sizes, int n_in,
                              void* d_out, int out_size, void* d_ws, size_t ws_size,
                              hipStream_t stream) {
  (void)in_sizes; (void)n_in; (void)out_size; (void)ws_size;
  const float* x   = (const float*)d_in[0];
  const float* ctx = (const float*)d_in[1];
  const unsigned char* mask = (const unsigned char*)d_in[2];
  const float* Wq = (const float*)d_in[3];
  const float* Wk = (const float*)d_in[4];
  const float* Wv = (const float*)d_in[5];
  const float* Wo = (const float*)d_in[6];
  const float* bo = (const float*)d_in[7];
  float* out = (float*)d_out;

  hipFuncSetAttribute((const void*)gemm_qproj_f,
                      hipFuncAttributeMaxDynamicSharedMemorySize, 73728);
  hipFuncSetAttribute((const void*)gemm_oproj_p,
                      hipFuncAttributeMaxDynamicSharedMemorySize, 98304);

  char* ws = (char*)d_ws;
  size_t off = 0;
  auto alloc = [&](size_t bytes) {
    char* p = ws + off;
    off += (bytes + 255) & ~(size_t)255;
    return p;
  };
  float*    biasT = (float*)alloc(B_SZ * 80 * sizeof(float));
  ushort_t* ab    = (ushort_t*)alloc((size_t)M_ROWS * INNER * 2);
  ushort_t* qb    = (ushort_t*)alloc((size_t)M_ROWS * INNER * 2);
  ushort_t* cb    = (ushort_t*)alloc((size_t)1280 * CDIM * 2);
  ushort_t* Wqb   = (ushort_t*)alloc((size_t)INNER * QDIM * 2);   // (0.125*Wq)^T [512][320]
  ushort_t* Wkvb  = (ushort_t*)alloc((size_t)1024 * CDIM * 2);    // [[Wk^T];[Wv^T]]
  ushort_t* Wob   = (ushort_t*)alloc((size_t)384 * INNER * 2);    // Wo^T pad [384][512]
  ushort_t* kvb   = (ushort_t*)alloc((size_t)1280 * 1024 * 2);
  ushort_t* vt    = (ushort_t*)alloc((size_t)B_SZ * HEADS * 64 * VT_STR * 2);

  mask_bias_kernel<<<1, 256, 0, stream>>>(mask, biasT);
  prep_kernel<<<2048, 256, 0, stream>>>(ctx, cb, Wq, Wqb, Wk, Wv, Wkvb, Wo, Wob);

  // q = bf16(x) @ (0.125*Wq) — f32-A direct, 2 blocks/CU, same-M adjacency
  gemm_qproj_f<<<dim3(4, M_ROWS / 128), 512, 73728, stream>>>(x, Wqb, qb);
  // [k|v] = ctx @ [Wk|Wv]
  dim3 g2(1280 / 128, 1024 / 128);
  gemm_bf16<<<g2, 256, 0, stream>>>(cb, Wkvb, kvb, CDIM, CDIM, CDIM, 1024);
  // V -> vt[b][h][d][104]
  vtrans_kernel<<<dim3(16, HEADS, B_SZ), 256, 0, stream>>>(kvb, vt);
  // attention
  attn_kernel<<<dim3(NQ / 256, HEADS, B_SZ), 256, 0, stream>>>(qb, kvb, vt, biasT, ab);
  // out = ab @ Wo + bo — pipelined
  gemm_oproj_p<<<M_ROWS / 128, 512, 98304, stream>>>(ab, Wob, bo, out);
}

// Round 20
// 180.253 us; speedup vs baseline: 1.0989x; 1.0989x over previous
//
#include <hip/hip_runtime.h>

typedef unsigned short ushort_t;
typedef __attribute__((ext_vector_type(8))) short bf16x8;
typedef __attribute__((ext_vector_type(4))) float f32x4;

#define B_SZ   16
#define NQ     4096
#define NKV    77
#define QDIM   320
#define CDIM   768
#define HEADS  8
#define DHEAD  64
#define INNER  512
#define M_ROWS (B_SZ * NQ)   // 65536
#define VT_STR 104

__device__ __forceinline__ ushort_t f2bf(float f) {
  unsigned u = __builtin_bit_cast(unsigned, f);
  u = (u + 0x7fffu + ((u >> 16) & 1u)) >> 16;
  return (ushort_t)u;
}

__device__ __forceinline__ void async16(const ushort_t* g, ushort_t* l) {
  __builtin_amdgcn_global_load_lds(
      (const __attribute__((address_space(1))) unsigned int*)g,
      (__attribute__((address_space(3))) unsigned int*)l,
      16, 0, 0);
}

__device__ __forceinline__ bf16x8 cvt8(f32x4 lo, f32x4 hi) {
  unsigned w0, w1, w2, w3;
  asm("v_cvt_pk_bf16_f32 %0, %1, %2" : "=v"(w0) : "v"(lo[0]), "v"(lo[1]));
  asm("v_cvt_pk_bf16_f32 %0, %1, %2" : "=v"(w1) : "v"(lo[2]), "v"(lo[3]));
  asm("v_cvt_pk_bf16_f32 %0, %1, %2" : "=v"(w2) : "v"(hi[0]), "v"(hi[1]));
  asm("v_cvt_pk_bf16_f32 %0, %1, %2" : "=v"(w3) : "v"(hi[2]), "v"(hi[3]));
  union { unsigned u[4]; bf16x8 v; } cv;
  cv.u[0] = w0; cv.u[1] = w1; cv.u[2] = w2; cv.u[3] = w3;
  return cv.v;
}

// ---------------- mask dtype detect + bias table ----------------
__global__ void mask_bias_kernel(const unsigned char* __restrict__ mraw,
                                 float* __restrict__ biasT) {
  __shared__ int s_u8, s_w4;
  if (threadIdx.x == 0) { s_u8 = 0; s_w4 = 0; }
  __syncthreads();
  const int nbytes = B_SZ * NKV;
  for (int i = threadIdx.x; i < nbytes; i += blockDim.x) {
    unsigned char v = mraw[i];
    if (v && (i & 3)) atomicOr(&s_u8, 1);
    if (v && ((i & 7) == 4)) atomicOr(&s_w4, 1);
  }
  __syncthreads();
  int mode = s_u8 ? 0 : (s_w4 ? 1 : 2);
  for (int i = threadIdx.x; i < B_SZ * 80; i += blockDim.x) {
    int b = i / 80, kv = i - b * 80;
    float bias = -2e30f;
    if (kv < NKV) {
      int idx = b * NKV + kv;
      long long m;
      if (mode == 0)      m = (long long)mraw[idx];
      else if (mode == 1) m = (long long)((const int*)mraw)[idx];
      else                m = ((const long long*)mraw)[idx];
      bias = m ? 0.0f : -1e30f;
    }
    biasT[i] = bias;
  }
}

// ---------------- fused prep: ctx cast + all weight transpose-casts --------
#define PREP_T0 236544
#define PREP_T1 400384
#define PREP_T2 1186816
#define PREP_T3 1383424
__global__ void prep_kernel(const float* __restrict__ ctx, ushort_t* __restrict__ cb,
                            const float* __restrict__ Wq, ushort_t* __restrict__ Wqb,
                            const float* __restrict__ Wk, const float* __restrict__ Wv,
                            ushort_t* __restrict__ Wkvb,
                            const float* __restrict__ Wo, ushort_t* __restrict__ Wob) {
  int i = blockIdx.x * blockDim.x + threadIdx.x;
  const int stride = gridDim.x * blockDim.x;
  for (; i < PREP_T3; i += stride) {
    if (i < PREP_T0) {
      float4 v = ((const float4*)ctx)[i];
      ushort4 o;
      o.x = f2bf(v.x); o.y = f2bf(v.y); o.z = f2bf(v.z); o.w = f2bf(v.w);
      ((ushort4*)cb)[i] = o;
    } else if (i < PREP_T1) {
      int j = i - PREP_T0;
      int n = j / QDIM, k = j - n * QDIM;
      Wqb[j] = f2bf(Wq[(size_t)k * INNER + n] * 0.125f);
    } else if (i < PREP_T2) {
      int j = i - PREP_T1;
      int n = j / CDIM, k = j - n * CDIM;
      float v = (n < INNER) ? Wk[(size_t)k * INNER + n]
                            : Wv[(size_t)k * INNER + (n - INNER)];
      Wkvb[j] = f2bf(v);
    } else {
      int j = i - PREP_T2;
      int n = j / INNER, k = j - n * INNER;
      Wob[j] = (n < QDIM) ? f2bf(Wo[(size_t)k * QDIM + n]) : (ushort_t)0;
    }
  }
}

// ---------------- generic 128x128 GEMM (kv projection only) ----------
__global__ __launch_bounds__(256) void gemm_bf16(
    const ushort_t* __restrict__ A, const ushort_t* __restrict__ Bt,
    ushort_t* __restrict__ Cb,
    int K, int Astride, int Bstride, int Cstride) {
  __shared__ ushort_t As[128 * 64];
  __shared__ ushort_t Bs[128 * 64];
  const int tid = threadIdx.x;
  const int wid = tid >> 6, lane = tid & 63;
  const int wr = wid >> 1, wc = wid & 1;
  const int tileM = blockIdx.x * 128, tileN = blockIdx.y * 128;

  f32x4 acc[4][4];
#pragma unroll
  for (int m = 0; m < 4; ++m)
#pragma unroll
    for (int n = 0; n < 4; ++n) acc[m][n] = (f32x4){0.f, 0.f, 0.f, 0.f};

  const int srow = lane >> 3;
  const int scol = (lane & 7) * 8;

  for (int kt = 0; kt < K; kt += 64) {
    __syncthreads();
#pragma unroll
    for (int j = 0; j < 4; ++j) {
      int s = wid * 4 + j;
      const ushort_t* ga = A + (size_t)(tileM + s * 8 + srow) * Astride + kt + scol;
      const ushort_t* gb = Bt + (size_t)(tileN + s * 8 + srow) * Bstride + kt + scol;
      async16(ga, As + s * 512);
      async16(gb, Bs + s * 512);
    }
    __syncthreads();
#pragma unroll
    for (int kc = 0; kc < 2; ++kc) {
      bf16x8 af[4], bfr[4];
#pragma unroll
      for (int m = 0; m < 4; ++m)
        af[m] = *(const bf16x8*)&As[(wr * 64 + m * 16 + (lane & 15)) * 64 + kc * 32 + (lane >> 4) * 8];
#pragma unroll
      for (int n = 0; n < 4; ++n)
        bfr[n] = *(const bf16x8*)&Bs[(wc * 64 + n * 16 + (lane & 15)) * 64 + kc * 32 + (lane >> 4) * 8];
#pragma unroll
      for (int m = 0; m < 4; ++m)
#pragma unroll
        for (int n = 0; n < 4; ++n)
          acc[m][n] = __builtin_amdgcn_mfma_f32_16x16x32_bf16(af[m], bfr[n], acc[m][n], 0, 0, 0);
    }
  }

  const int r0 = tileM + wr * 64;
  const int c0 = tileN + wc * 64;
  const int rl2 = (lane >> 4) * 4;
  const int cl = lane & 15;
#pragma unroll
  for (int m = 0; m < 4; ++m)
#pragma unroll
    for (int n = 0; n < 4; ++n) {
      int col = c0 + n * 16 + cl;
#pragma unroll
      for (int r = 0; r < 4; ++r)
        Cb[(size_t)(r0 + m * 16 + rl2 + r) * Cstride + col] = f2bf(acc[m][n][r]);
    }
}

__global__ void vtrans_kernel(const ushort_t* __restrict__ kvb,
                              ushort_t* __restrict__ vt) {
  const int h = blockIdx.y, b = blockIdx.z;
  const int wid = threadIdx.x >> 6, lane = threadIdx.x & 63;
  const int d = blockIdx.x * 4 + wid;
  ushort_t* dst = vt + (size_t)(b * HEADS + h) * (64 * VT_STR) + d * VT_STR;
  for (int kv = lane; kv < VT_STR; kv += 64)
    dst[kv] = (kv < NKV)
        ? kvb[(size_t)(b * NKV + kv) * 1024 + 512 + h * 64 + d]
        : (ushort_t)0;
}

// ---------------- q-proj: 2-buffer, __syncthreads-safe pipeline ------------
// 512 blocks x (128 rows x full N=512). 8 waves (2M x 4N). BK=32, 10 steps.
// Stage(s+1) issued before compute(s); the step-end __syncthreads (vmcnt(0)
// drain, full fence) makes all cross-wave LDS hand-offs safe by construction.
__global__ __launch_bounds__(512, 2) void gemm_qproj_p(
    const float* __restrict__ x, const ushort_t* __restrict__ Wt,
    ushort_t* __restrict__ qb) {
  extern __shared__ char sm[];
  const int tid = threadIdx.x, wid = tid >> 6, lane = tid & 63;
  const int rl = lane & 15, g = lane >> 4;
  const int wr = wid & 1, wc = wid >> 1;
  const size_t Mbase = (size_t)blockIdx.x * 128;

  size_t asrc[2]; unsigned adst[2];
#pragma unroll
  for (int i = 0; i < 2; ++i) {
    int c = tid + i * 512, row = c >> 3, c16 = c & 7;
    asrc[i] = (Mbase + row) * 1280 + (unsigned)((c16 * 16) ^ ((row & 7) << 4));
    adst[i] = c * 16;
  }
  size_t bsrc[4]; unsigned bdst[4];
#pragma unroll
  for (int i = 0; i < 4; ++i) {
    int c = tid + i * 512, row = c >> 2, c16 = c & 3;
    bsrc[i] = (size_t)row * 640 + (unsigned)((c16 * 16) ^ ((row & 3) << 4));
    bdst[i] = 16384 + c * 16;
  }
  const char* xB = (const char*)x;
  const char* WtB = (const char*)Wt;

  f32x4 acc[4][8];
#pragma unroll
  for (int m = 0; m < 4; ++m)
#pragma unroll
    for (int n = 0; n < 8; ++n) acc[m][n] = (f32x4){0.f, 0.f, 0.f, 0.f};

#define QSTAGE(K)                                                           \
  {                                                                         \
    char* bb = sm + (unsigned)((K) & 1) * 49152u;                           \
    _Pragma("unroll")                                                       \
    for (int i = 0; i < 2; ++i)                                             \
      async16((const ushort_t*)(xB + asrc[i] + (size_t)(K) * 128),          \
              (ushort_t*)(bb + adst[i]));                                   \
    _Pragma("unroll")                                                       \
    for (int i = 0; i < 4; ++i)                                             \
      async16((const ushort_t*)(WtB + bsrc[i] + (size_t)(K) * 64),          \
              (ushort_t*)(bb + bdst[i]));                                   \
  }

  QSTAGE(0)
  __syncthreads();                 // buf0 resident
  for (int s = 0; s < 10; ++s) {
    if (s < 9) QSTAGE(s + 1)       // prefetch next buf; overlaps compute below

    const char* Ab = sm + (unsigned)(s & 1) * 49152u;
    const char* Bb = Ab + 16384;
    bf16x8 af[4], bfr[8];
#pragma unroll
    for (int m = 0; m < 4; ++m) {
      const int row = wr * 64 + m * 16 + rl;
      const int sw = (row & 7) << 4;
      f32x4 lo = *(const f32x4*)(Ab + row * 128 + ((g * 32) ^ sw));
      f32x4 hi = *(const f32x4*)(Ab + row * 128 + ((g * 32 + 16) ^ sw));
      af[m] = cvt8(lo, hi);
    }
#pragma unroll
    for (int n = 0; n < 8; ++n) {
      const int row = wc * 128 + n * 16 + rl;
      bfr[n] = *(const bf16x8*)(Bb + row * 64 + ((g * 16) ^ ((row & 3) << 4)));
    }
#pragma unroll
    for (int m = 0; m < 4; ++m)
#pragma unroll
      for (int n = 0; n < 8; ++n)
        acc[m][n] = __builtin_amdgcn_mfma_f32_16x16x32_bf16(af[m], bfr[n], acc[m][n], 0, 0, 0);

    __syncthreads();               // reads(s) done; stage(s+1) writes landed
  }

  // epilogue: acc -> LDS (bf16) -> coalesced 16B stores, 2 halves of 64 rows
  ushort_t* eb = (ushort_t*)sm;
#pragma unroll
  for (int h = 0; h < 2; ++h) {
    if (h) __syncthreads();
    if (wr == h) {
#pragma unroll
      for (int m = 0; m < 4; ++m)
#pragma unroll
        for (int n = 0; n < 8; ++n)
#pragma unroll
          for (int r = 0; r < 4; ++r)
            eb[(m * 16 + g * 4 + r) * 512 + wc * 128 + n * 16 + rl] = f2bf(acc[m][n][r]);
    }
    __syncthreads();
#pragma unroll
    for (int i = 0; i < 8; ++i) {
      int c = tid + i * 512, row = c >> 6;
      *(bf16x8*)(qb + (Mbase + h * 64 + row) * 512 + (c & 63) * 8) =
          *(const bf16x8*)(eb + c * 8);
    }
  }
}

// ---------------- out-proj: 2-buffer, __syncthreads-safe pipeline ----------
// 512 blocks x (128 rows x full N=384). 8 waves (2M x 4N). BK=32, 16 steps.
__global__ __launch_bounds__(512, 2) void gemm_oproj_p(
    const ushort_t* __restrict__ A, const ushort_t* __restrict__ Wt,
    const float* __restrict__ bo, float* __restrict__ out) {
  extern __shared__ char sm[];
  const int tid = threadIdx.x, wid = tid >> 6, lane = tid & 63;
  const int rl = lane & 15, g = lane >> 4;
  const int wr = wid & 1, wc = wid >> 1;
  const size_t Mbase = (size_t)blockIdx.x * 128;

  size_t asrc; unsigned adst;
  {
    int c = tid, row = c >> 2, c16 = c & 3;
    asrc = (Mbase + row) * 1024 + (unsigned)((c16 * 16) ^ ((row & 3) << 4));
    adst = c * 16;
  }
  size_t bsrc[3]; unsigned bdst[3];
#pragma unroll
  for (int i = 0; i < 3; ++i) {
    int c = tid + i * 512, row = c >> 2, c16 = c & 3;
    bsrc[i] = (size_t)row * 1024 + (unsigned)((c16 * 16) ^ ((row & 3) << 4));
    bdst[i] = 8192 + c * 16;
  }
  const char* AB = (const char*)A;
  const char* WtB = (const char*)Wt;

  f32x4 acc[4][6];
#pragma unroll
  for (int m = 0; m < 4; ++m)
#pragma unroll
    for (int n = 0; n < 6; ++n) acc[m][n] = (f32x4){0.f, 0.f, 0.f, 0.f};

#define OSTAGE(K)                                                           \
  {                                                                         \
    char* bb = sm + (unsigned)((K) & 1) * 32768u;                           \
    async16((const ushort_t*)(AB + asrc + (size_t)(K) * 64),                \
            (ushort_t*)(bb + adst));                                        \
    _Pragma("unroll")                                                       \
    for (int i = 0; i < 3; ++i)                                             \
      async16((const ushort_t*)(WtB + bsrc[i] + (size_t)(K) * 64),          \
              (ushort_t*)(bb + bdst[i]));                                   \
  }

  OSTAGE(0)
  __syncthreads();                 // buf0 resident
  for (int s = 0; s < 16; ++s) {
    if (s < 15) OSTAGE(s + 1)      // prefetch next buf; overlaps compute below

    const char* Ab = sm + (unsigned)(s & 1) * 32768u;
    const char* Bb = Ab + 8192;
    bf16x8 af[4], bfr[6];
#pragma unroll
    for (int m = 0; m < 4; ++m) {
      const int row = wr * 64 + m * 16 + rl;
      af[m] = *(const bf16x8*)(Ab + row * 64 + ((g * 16) ^ ((row & 3) << 4)));
    }
#pragma unroll
    for (int n = 0; n < 6; ++n) {
      const int row = wc * 96 + n * 16 + rl;
      bfr[n] = *(const bf16x8*)(Bb + row * 64 + ((g * 16) ^ ((row & 3) << 4)));
    }
#pragma unroll
    for (int m = 0; m < 4; ++m)
#pragma unroll
      for (int n = 0; n < 6; ++n)
        acc[m][n] = __builtin_amdgcn_mfma_f32_16x16x32_bf16(af[m], bfr[n], acc[m][n], 0, 0, 0);

    __syncthreads();               // reads(s) done; stage(s+1) writes landed
  }

  const size_t r0 = Mbase + wr * 64;
  const int c0 = wc * 96;
#pragma unroll
  for (int n = 0; n < 6; ++n) {
    int col = c0 + n * 16 + rl;
    if (col < QDIM) {
      float bv = bo[col];
#pragma unroll
      for (int m = 0; m < 4; ++m)
#pragma unroll
        for (int r = 0; r < 4; ++r)
          out[(r0 + m * 16 + g * 4 + r) * QDIM + col] = acc[m][n][r] + bv;
    }
  }
}

// ---------------- fused attention (r2 version, unchanged) ----------------
__global__ __launch_bounds__(256) void attn_kernel(
    const ushort_t* __restrict__ qb, const ushort_t* __restrict__ kvb,
    const ushort_t* __restrict__ vt, const float* __restrict__ biasT,
    ushort_t* __restrict__ ab) {
  __shared__ ushort_t Vt[64 * VT_STR];
  __shared__ ushort_t P[4 * 16 * VT_STR];
  const int qt = blockIdx.x, h = blockIdx.y, b = blockIdx.z;
  const int tid = threadIdx.x, wid = tid >> 6, lane = tid & 63;
  const int rl = lane & 15;
  const int kh = (lane >> 4) * 8;

  const ushort_t* vtg = vt + (size_t)(b * HEADS + h) * (64 * VT_STR);
  for (int i = tid; i < 832; i += 256) async16(vtg + i * 8, Vt + i * 8);
  for (int i = tid; i < 832; i += 256)
    *(bf16x8*)&P[i * 8] = (bf16x8){0, 0, 0, 0, 0, 0, 0, 0};

  bf16x8 kf[5][2];
  float bias_v[5];
#pragma unroll
  for (int nt = 0; nt < 5; ++nt) {
    int kv = nt * 16 + rl;
    bias_v[nt] = biasT[b * 80 + kv];
    kf[nt][0] = (bf16x8){0, 0, 0, 0, 0, 0, 0, 0};
    kf[nt][1] = (bf16x8){0, 0, 0, 0, 0, 0, 0, 0};
    if (kv < NKV) {
      const ushort_t* kp = &kvb[(size_t)(b * NKV + kv) * 1024 + h * 64 + kh];
      kf[nt][0] = *(const bf16x8*)kp;
      kf[nt][1] = *(const bf16x8*)(kp + 32);
    }
  }
  __syncthreads();

  const int qbase = b * NQ + qt * 256;
  const int pbase = wid * (16 * VT_STR);
#pragma unroll 1
  for (int chunk = 0; chunk < 4; ++chunk) {
    if (chunk) __syncthreads();
    const int row0 = chunk * 64 + wid * 16;

    const ushort_t* qp = &qb[(size_t)(qbase + row0 + rl) * INNER + h * 64 + kh];
    bf16x8 qf0 = *(const bf16x8*)qp;
    bf16x8 qf1 = *(const bf16x8*)(qp + 32);

    f32x4 s[5];
#pragma unroll
    for (int nt = 0; nt < 5; ++nt) {
      s[nt] = (f32x4){0.f, 0.f, 0.f, 0.f};
      s[nt] = __builtin_amdgcn_mfma_f32_16x16x32_bf16(qf0, kf[nt][0], s[nt], 0, 0, 0);
      s[nt] = __builtin_amdgcn_mfma_f32_16x16x32_bf16(qf1, kf[nt][1], s[nt], 0, 0, 0);
    }

    float mx[4] = {-3.0e38f, -3.0e38f, -3.0e38f, -3.0e38f};
#pragma unroll
    for (int nt = 0; nt < 5; ++nt)
#pragma unroll
      for (int r = 0; r < 4; ++r) {
        float v = s[nt][r] + bias_v[nt];
        s[nt][r] = v;
        mx[r] = fmaxf(mx[r], v);
      }
#pragma unroll
    for (int d = 1; d < 16; d <<= 1)
#pragma unroll
      for (int r = 0; r < 4; ++r) mx[r] = fmaxf(mx[r], __shfl_xor(mx[r], d, 64));

    float sm_[4] = {0.f, 0.f, 0.f, 0.f};
#pragma unroll
    for (int nt = 0; nt < 5; ++nt)
#pragma unroll
      for (int r = 0; r < 4; ++r) {
        float p = __expf(s[nt][r] - mx[r]);
        s[nt][r] = p;
        sm_[r] += p;
      }
#pragma unroll
    for (int d = 1; d < 16; d <<= 1)
#pragma unroll
      for (int r = 0; r < 4; ++r) sm_[r] += __shfl_xor(sm_[r], d, 64);

    float rcp[4];
#pragma unroll
    for (int r = 0; r < 4; ++r) rcp[r] = 1.0f / sm_[r];

#pragma unroll
    for (int nt = 0; nt < 5; ++nt)
#pragma unroll
      for (int r = 0; r < 4; ++r)
        P[pbase + ((lane >> 4) * 4 + r) * VT_STR + nt * 16 + rl] = f2bf(s[nt][r]);

    f32x4 o[4];
#pragma unroll
    for (int n = 0; n < 4; ++n) o[n] = (f32x4){0.f, 0.f, 0.f, 0.f};
#pragma unroll
    for (int kc = 0; kc < 3; ++kc) {
      bf16x8 pf = *(const bf16x8*)&P[pbase + rl * VT_STR + kc * 32 + kh];
#pragma unroll
      for (int n = 0; n < 4; ++n) {
        bf16x8 vf = *(const bf16x8*)&Vt[(n * 16 + rl) * VT_STR + kc * 32 + kh];
        o[n] = __builtin_amdgcn_mfma_f32_16x16x32_bf16(pf, vf, o[n], 0, 0, 0);
      }
    }

#pragma unroll
    for (int n = 0; n < 4; ++n)
#pragma unroll
      for (int r = 0; r < 4; ++r)
        P[pbase + ((lane >> 4) * 4 + r) * VT_STR + n * 16 + rl] = f2bf(o[n][r] * rcp[r]);

    __syncthreads();

    {
      const int rflat = tid >> 2, d0 = (tid & 3) * 16;
      const ushort_t* src = &P[(rflat >> 4) * (16 * VT_STR) + (rflat & 15) * VT_STR + d0];
      ushort_t* dst = &ab[(size_t)(qbase + chunk * 64 + rflat) * INNER + h * 64 + d0];
      *(bf16x8*)dst = *(const bf16x8*)src;
      *(bf16x8*)(dst + 8) = *(const bf16x8*)(src + 8);
    }
  }
}

// ---------------- host ----------------
extern "C" void kernel_launch(void* const* d_in, const int* in_sizes, int n_in,
                              void* d_out, int out_size, void* d_ws, size_t ws_size,
                              hipStream_t stream) {
  (void)in_sizes; (void)n_in; (void)out_size; (void)ws_size;
  const float* x   = (const float*)d_in[0];
  const float* ctx = (const float*)d_in[1];
  const unsigned char* mask = (const unsigned char*)d_in[2];
  const float* Wq = (const float*)d_in[3];
  const float* Wk = (const float*)d_in[4];
  const float* Wv = (const float*)d_in[5];
  const float* Wo = (const float*)d_in[6];
  const float* bo = (const float*)d_in[7];
  float* out = (float*)d_out;

  hipFuncSetAttribute((const void*)gemm_qproj_p,
                      hipFuncAttributeMaxDynamicSharedMemorySize, 98304);
  hipFuncSetAttribute((const void*)gemm_oproj_p,
                      hipFuncAttributeMaxDynamicSharedMemorySize, 65536);

  char* ws = (char*)d_ws;
  size_t off = 0;
  auto alloc = [&](size_t bytes) {
    char* p = ws + off;
    off += (bytes + 255) & ~(size_t)255;
    return p;
  };
  float*    biasT = (float*)alloc(B_SZ * 80 * sizeof(float));
  ushort_t* ab    = (ushort_t*)alloc((size_t)M_ROWS * INNER * 2);
  ushort_t* qb    = (ushort_t*)alloc((size_t)M_ROWS * INNER * 2);
  ushort_t* cb    = (ushort_t*)alloc((size_t)1280 * CDIM * 2);
  ushort_t* Wqb   = (ushort_t*)alloc((size_t)INNER * QDIM * 2);   // (0.125*Wq)^T [512][320]
  ushort_t* Wkvb  = (ushort_t*)alloc((size_t)1024 * CDIM * 2);    // [[Wk^T];[Wv^T]]
  ushort_t* Wob   = (ushort_t*)alloc((size_t)384 * INNER * 2);    // Wo^T pad [384][512]
  ushort_t* kvb   = (ushort_t*)alloc((size_t)1280 * 1024 * 2);
  ushort_t* vt    = (ushort_t*)alloc((size_t)B_SZ * HEADS * 64 * VT_STR * 2);

  mask_bias_kernel<<<1, 256, 0, stream>>>(mask, biasT);
  prep_kernel<<<2048, 256, 0, stream>>>(ctx, cb, Wq, Wqb, Wk, Wv, Wkvb, Wo, Wob);

  // q = bf16(x) @ (0.125*Wq) — 2-buffer safe pipeline, x read exactly once
  gemm_qproj_p<<<M_ROWS / 128, 512, 98304, stream>>>(x, Wqb, qb);
  // [k|v] = ctx @ [Wk|Wv]
  dim3 g2(1280 / 128, 1024 / 128);
  gemm_bf16<<<g2, 256, 0, stream>>>(cb, Wkvb, kvb, CDIM, CDIM, CDIM, 1024);
  // V -> vt[b][h][d][104]
  vtrans_kernel<<<dim3(16, HEADS, B_SZ), 256, 0, stream>>>(kvb, vt);
  // attention
  attn_kernel<<<dim3(NQ / 256, HEADS, B_SZ), 256, 0, stream>>>(qb, kvb, vt, biasT, ab);
  // out = ab @ Wo + bo — 2-buffer safe pipeline
  gemm_oproj_p<<<M_ROWS / 128, 512, 65536, stream>>>(ab, Wob, bo, out);
}